// Round 5
// baseline (397.128 us; speedup 1.0000x reference)
//
#include <hip/hip_runtime.h>
#include <math.h>

#define BB 4
#define CC 64
#define OO 64
#define HH 128
#define WWD 128
#define HWP (HH*WWD)   // 16384

typedef short bf16x8 __attribute__((ext_vector_type(8)));
typedef float f32x4  __attribute__((ext_vector_type(4)));

__device__ __forceinline__ unsigned short bf16_rne(float f) {
    unsigned u = __float_as_uint(f);
    u += 0x7fffu + ((u >> 16) & 1u);
    return (unsigned short)(u >> 16);
}
__device__ __forceinline__ float bf16_tof(unsigned short h) {
    return __uint_as_float((unsigned)h << 16);
}

// ---------------------------------------------------------------------------
// Kernel 1: W[o][c][3][3] fp32 -> Whi/Wlo[k][o][c] bf16 hi/lo split, both
// layers. grid: 288 x 256 = 73728 = 2 * 64*64*9
// ---------------------------------------------------------------------------
__global__ __launch_bounds__(256) void wtrans_kernel(
    const float* __restrict__ W1, const float* __restrict__ W2,
    unsigned short* __restrict__ Wh1, unsigned short* __restrict__ Wl1,
    unsigned short* __restrict__ Wh2, unsigned short* __restrict__ Wl2)
{
    int idx = blockIdx.x * 256 + threadIdx.x;
    const int n = OO * CC * 9;           // 36864
    const float* src;
    unsigned short *dh, *dl;
    if (idx >= n) { src = W2; dh = Wh2; dl = Wl2; idx -= n; }
    else          { src = W1; dh = Wh1; dl = Wl1; }
    int c = idx & 63;
    int o = (idx >> 6) & 63;
    int k = idx >> 12;
    float w = src[(o * CC + c) * 9 + k];
    unsigned short hi = bf16_rne(w);
    unsigned short lo = bf16_rne(w - bf16_tof(hi));
    dh[idx] = hi;
    dl[idx] = lo;
}

// ---------------------------------------------------------------------------
// Kernel 2: FUSED offsets-conv + arconv, barrier-free main loop, hi/lo
// 3-product MFMA numerics (the round-3-verified compensation).
// grid: 1024 blocks x 256 threads. Block = (batch b, 64-px row segment).
// Phase 0 (once): conv3x3(x,w_off)+sigmoid -> rf per pixel (LDS reduce).
// Phase 1 (9 taps, NO barriers, NO LDS): thread (nidx,quad) of wave wv
// bilinear-samples pixel wv*16+nidx, channels {quad*8+j, 32+quad*8+j},
// hi/lo-split DIRECTLY into B-fragments; A hi/lo fragments stream from
// L1-hot Whi/Wlo[k][o][c]; 24 MFMAs/tap: Wh*Sh + Wl*Sh + Wh*Sl.
// mode 1: out = relu(acc+bias). mode 2: out = resid + acc + bias.
// ---------------------------------------------------------------------------
__global__ __launch_bounds__(256) void arconv_kernel(
    const float*          __restrict__ xin,   // [B,C,H,W]
    const unsigned short* __restrict__ Whi,   // [9][O][C] bf16 hi
    const unsigned short* __restrict__ Wlo,   // [9][O][C] bf16 lo
    const float*          __restrict__ woff,  // [2,C,3,3]
    const float*          __restrict__ boff,  // [2]
    const float*          __restrict__ bias,  // [O]
    const int* __restrict__ lo_p, const int* __restrict__ hi_p,
    const float* __restrict__ resid,
    float* __restrict__ out, int mode)
{
    __shared__ float swo[2 * CC * 9];    // offset-conv weights, 4.5 KB
    __shared__ float red[2][4][64];      // c-quarter partials, 2 KB
    __shared__ float rfs[2][64];         // rf_h/2, rf_w/2 per pixel

    int t    = threadIdx.x;
    int blk  = blockIdx.x;
    int b    = blk >> 8;
    int tile = blk & 255;
    int p0   = tile * 64;
    int y    = p0 >> 7;          // all 64 px share one row
    int xb   = p0 & 127;

    // ---------------- phase 0: fused offsets conv ----------------
    for (int i = t; i < 2 * CC * 9; i += 256) swo[i] = woff[i];

    int p   = t & 63;
    int cq  = t >> 6;
    int xx0 = xb + p;
    __syncthreads();

    const float* xb_ptr = xin + (size_t)b * CC * HWP;
    {
        float a0 = 0.f, a1 = 0.f;
        for (int c = cq * 16; c < cq * 16 + 16; ++c) {
            const float* xc = xb_ptr + c * HWP;
            const float* w0 = swo + (0 * CC + c) * 9;
            const float* w1 = swo + (1 * CC + c) * 9;
#pragma unroll
            for (int ky = 0; ky < 3; ++ky) {
                int yy = y + ky - 1;
                bool yok = (yy >= 0) && (yy < HH);
#pragma unroll
                for (int kx = 0; kx < 3; ++kx) {
                    int xx = xx0 + kx - 1;
                    float v = 0.f;
                    if (yok && xx >= 0 && xx < WWD) v = xc[yy * WWD + xx];
                    a0 = fmaf(v, w0[ky * 3 + kx], a0);
                    a1 = fmaf(v, w1[ky * 3 + kx], a1);
                }
            }
        }
        red[0][cq][p] = a0;
        red[1][cq][p] = a1;
    }
    __syncthreads();
    if (t < 128) {
        int ch = t >> 6;       // 0 = h, 1 = w
        int pp = t & 63;
        float flo = (float)lo_p[0];
        float fhi = (float)hi_p[0];
        float s = red[ch][0][pp] + red[ch][1][pp] + red[ch][2][pp]
                + red[ch][3][pp] + boff[ch];
        float g = 1.f / (1.f + expf(-s));
        rfs[ch][pp] = (flo + (fhi - flo) * g) * 0.5f;   // pre-halved
    }
    __syncthreads();

    // ---------------- phase 1: barrier-free sample + MFMA ----------------
    int lane = t & 63;
    int wv   = t >> 6;
    int nidx = lane & 15;
    int quad = lane >> 4;
    int px   = wv * 16 + nidx;       // this thread's pixel in the segment

    float rh = rfs[0][px];
    float rw = rfs[1][px];
    float fy = (float)y;
    float fx = (float)(xb + px);
    const float* xc0 = xin + (size_t)b * CC * HWP + (size_t)(quad * 8) * HWP;

    f32x4 acc[4] = {};

    for (int k = 0; k < 9; ++k) {
        float dy = (float)(k / 3 - 1);
        float dx = (float)(k % 3 - 1);
        float ys = fy + dy * rh;
        float xs = fx + dx * rw;
        float y0f = floorf(ys), x0f = floorf(xs);
        float ty = ys - y0f, tx = xs - x0f;
        int iy0 = min(max((int)y0f, 0), HH - 1);
        int iy1 = min(iy0 + 1, HH - 1);
        int ix0 = min(max((int)x0f, 0), WWD - 1);
        int ix1 = min(ix0 + 1, WWD - 1);
        float w00 = (1.f - ty) * (1.f - tx);
        float w01 = (1.f - ty) * tx;
        float w10 = ty * (1.f - tx);
        float w11 = ty * tx;
        int o00 = iy0 * WWD + ix0, o01 = iy0 * WWD + ix1;
        int o10 = iy1 * WWD + ix0, o11 = iy1 * WWD + ix1;

        // sample 16 channels straight into hi/lo B-fragments
        union { unsigned short h[8]; bf16x8 v; } b0h, b0l, b1h, b1l;
        {
            const float* xc = xc0;
#pragma unroll
            for (int j = 0; j < 8; ++j) {
                float s = w00 * xc[o00] + w01 * xc[o01]
                        + w10 * xc[o10] + w11 * xc[o11];
                unsigned short hs = bf16_rne(s);
                b0h.h[j] = hs;
                b0l.h[j] = bf16_rne(s - bf16_tof(hs));
                xc += HWP;
            }
            xc = xc0 + (size_t)32 * HWP;
#pragma unroll
            for (int j = 0; j < 8; ++j) {
                float s = w00 * xc[o00] + w01 * xc[o01]
                        + w10 * xc[o10] + w11 * xc[o11];
                unsigned short hs = bf16_rne(s);
                b1h.h[j] = hs;
                b1l.h[j] = bf16_rne(s - bf16_tof(hs));
                xc += HWP;
            }
        }

        // A hi/lo fragments from global (L1-hot: 16 KB working set per tap)
        const unsigned short* whk = Whi + (size_t)k * OO * CC + nidx * CC + quad * 8;
        const unsigned short* wlk = Wlo + (size_t)k * OO * CC + nidx * CC + quad * 8;
#pragma unroll
        for (int mt = 0; mt < 4; ++mt) {
            bf16x8 ah0 = *(const bf16x8*)(whk + mt * 16 * CC);        // ks=0
            bf16x8 al0 = *(const bf16x8*)(wlk + mt * 16 * CC);
            acc[mt] = __builtin_amdgcn_mfma_f32_16x16x32_bf16(ah0, b0h.v, acc[mt], 0, 0, 0);
            acc[mt] = __builtin_amdgcn_mfma_f32_16x16x32_bf16(al0, b0h.v, acc[mt], 0, 0, 0);
            acc[mt] = __builtin_amdgcn_mfma_f32_16x16x32_bf16(ah0, b0l.v, acc[mt], 0, 0, 0);
            bf16x8 ah1 = *(const bf16x8*)(whk + mt * 16 * CC + 32);   // ks=1
            bf16x8 al1 = *(const bf16x8*)(wlk + mt * 16 * CC + 32);
            acc[mt] = __builtin_amdgcn_mfma_f32_16x16x32_bf16(ah1, b1h.v, acc[mt], 0, 0, 0);
            acc[mt] = __builtin_amdgcn_mfma_f32_16x16x32_bf16(al1, b1h.v, acc[mt], 0, 0, 0);
            acc[mt] = __builtin_amdgcn_mfma_f32_16x16x32_bf16(ah1, b1l.v, acc[mt], 0, 0, 0);
        }
    }

    // ---------------- epilogue ----------------
    int pxg = p0 + px;
#pragma unroll
    for (int mt = 0; mt < 4; ++mt) {
#pragma unroll
        for (int r = 0; r < 4; ++r) {
            int o = mt * 16 + quad * 4 + r;
            float v = acc[mt][r] + bias[o];
            size_t idx = (size_t)(b * OO + o) * HWP + pxg;
            if (mode == 1) v = fmaxf(v, 0.f);
            else           v += resid[idx];
            out[idx] = v;
        }
    }
}

// ---------------------------------------------------------------------------
extern "C" void kernel_launch(void* const* d_in, const int* in_sizes, int n_in,
                              void* d_out, int out_size, void* d_ws, size_t ws_size,
                              hipStream_t stream) {
    const float* x      = (const float*)d_in[0];
    const float* w_off1 = (const float*)d_in[1];
    const float* b_off1 = (const float*)d_in[2];
    const float* W1     = (const float*)d_in[3];
    const float* b1     = (const float*)d_in[4];
    const float* w_off2 = (const float*)d_in[5];
    const float* b_off2 = (const float*)d_in[6];
    const float* W2     = (const float*)d_in[7];
    const float* b2     = (const float*)d_in[8];
    const int*   lo_p   = (const int*)d_in[10];
    const int*   hi_p   = (const int*)d_in[11];
    float* outp = (float*)d_out;

    float* wsf = (float*)d_ws;
    float* t1  = wsf;                                        // B*C*HW f32
    unsigned short* Wh1 = (unsigned short*)(t1 + (size_t)BB * CC * HWP);
    unsigned short* Wl1 = Wh1 + OO * CC * 9;                 // 36864 each
    unsigned short* Wh2 = Wl1 + OO * CC * 9;
    unsigned short* Wl2 = Wh2 + OO * CC * 9;

    // 1. transpose + hi/lo split both weight tensors
    wtrans_kernel<<<288, 256, 0, stream>>>(W1, W2, Wh1, Wl1, Wh2, Wl2);

    // 2. layer 1: fused offsets + arconv + relu -> t1
    arconv_kernel<<<1024, 256, 0, stream>>>(x, Wh1, Wl1, w_off1, b_off1, b1,
                                            lo_p, hi_p, nullptr, t1, 1);

    // 3. layer 2: fused offsets + arconv + residual -> out
    arconv_kernel<<<1024, 256, 0, stream>>>(t1, Wh2, Wl2, w_off2, b_off2, b2,
                                            lo_p, hi_p, x, outp, 2);
}

// Round 6
// 371.500 us; speedup vs baseline: 1.0690x; 1.0690x over previous
//
#include <hip/hip_runtime.h>
#include <math.h>

#define BB 4
#define CC 64
#define OO 64
#define HH 128
#define WWD 128
#define HWP (HH*WWD)   // 16384

typedef short bf16x8 __attribute__((ext_vector_type(8)));
typedef float f32x4  __attribute__((ext_vector_type(4)));

__device__ __forceinline__ unsigned short bf16_rne(float f) {
    unsigned u = __float_as_uint(f);
    u += 0x7fffu + ((u >> 16) & 1u);
    return (unsigned short)(u >> 16);
}
__device__ __forceinline__ float bf16_tof(unsigned short h) {
    return __uint_as_float((unsigned)h << 16);
}

// ---------------------------------------------------------------------------
// Kernel 1: W[o][c][3][3] fp32 -> Whi/Wlo[k][o][c] bf16 hi/lo split, both
// layers. grid: 288 x 256 = 73728 = 2 * 64*64*9
// ---------------------------------------------------------------------------
__global__ __launch_bounds__(256) void wtrans_kernel(
    const float* __restrict__ W1, const float* __restrict__ W2,
    unsigned short* __restrict__ Wh1, unsigned short* __restrict__ Wl1,
    unsigned short* __restrict__ Wh2, unsigned short* __restrict__ Wl2)
{
    int idx = blockIdx.x * 256 + threadIdx.x;
    const int n = OO * CC * 9;           // 36864
    const float* src;
    unsigned short *dh, *dl;
    if (idx >= n) { src = W2; dh = Wh2; dl = Wl2; idx -= n; }
    else          { src = W1; dh = Wh1; dl = Wl1; }
    int c = idx & 63;
    int o = (idx >> 6) & 63;
    int k = idx >> 12;
    float w = src[(o * CC + c) * 9 + k];
    unsigned short hi = bf16_rne(w);
    unsigned short lo = bf16_rne(w - bf16_tof(hi));
    dh[idx] = hi;
    dl[idx] = lo;
}

// ---------------------------------------------------------------------------
// Kernel 2: FUSED offsets-conv + arconv, barrier-free main loop, hi/lo
// 3-product MFMA numerics. XCD-AWARE BLOCK SWIZZLE (new this round):
// blockIdx & 7 selects a data slab = (2 batches x 32 image rows), so each
// XCD's ~128 co-resident blocks share a ~2.7 MB working set that fits its
// private 4 MB L2 (tap re-touches become L2 hits instead of HBM fetches).
// mode 1: out = relu(acc+bias). mode 2: out = resid + acc + bias.
// ---------------------------------------------------------------------------
__global__ __launch_bounds__(256) void arconv_kernel(
    const float*          __restrict__ xin,   // [B,C,H,W]
    const unsigned short* __restrict__ Whi,   // [9][O][C] bf16 hi
    const unsigned short* __restrict__ Wlo,   // [9][O][C] bf16 lo
    const float*          __restrict__ woff,  // [2,C,3,3]
    const float*          __restrict__ boff,  // [2]
    const float*          __restrict__ bias,  // [O]
    const int* __restrict__ lo_p, const int* __restrict__ hi_p,
    const float* __restrict__ resid,
    float* __restrict__ out, int mode)
{
    __shared__ float swo[2 * CC * 9];    // offset-conv weights, 4.5 KB
    __shared__ float red[2][4][64];      // c-quarter partials, 2 KB
    __shared__ float rfs[2][64];         // rf_h/2, rf_w/2 per pixel

    int t = threadIdx.x;

    // ---- XCD-aware swizzle: g&7 = slab (XCD via %8 round-robin dispatch) ----
    int g    = blockIdx.x;
    int s    = g & 7;
    int r    = g >> 3;                       // [0,128): 2 batches x 64 tiles
    int b    = ((s >> 2) << 1) | (r >> 6);   // batch
    int tile = ((s & 3) << 6) | (r & 63);    // tile in [0,256)
    int p0   = tile * 64;
    int y    = p0 >> 7;          // all 64 px share one row
    int xb   = p0 & 127;

    // ---------------- phase 0: fused offsets conv ----------------
    for (int i = t; i < 2 * CC * 9; i += 256) swo[i] = woff[i];

    int p   = t & 63;
    int cq  = t >> 6;
    int xx0 = xb + p;
    __syncthreads();

    const float* xb_ptr = xin + (size_t)b * CC * HWP;
    {
        float a0 = 0.f, a1 = 0.f;
        for (int c = cq * 16; c < cq * 16 + 16; ++c) {
            const float* xc = xb_ptr + c * HWP;
            const float* w0 = swo + (0 * CC + c) * 9;
            const float* w1 = swo + (1 * CC + c) * 9;
#pragma unroll
            for (int ky = 0; ky < 3; ++ky) {
                int yy = y + ky - 1;
                bool yok = (yy >= 0) && (yy < HH);
#pragma unroll
                for (int kx = 0; kx < 3; ++kx) {
                    int xx = xx0 + kx - 1;
                    float v = 0.f;
                    if (yok && xx >= 0 && xx < WWD) v = xc[yy * WWD + xx];
                    a0 = fmaf(v, w0[ky * 3 + kx], a0);
                    a1 = fmaf(v, w1[ky * 3 + kx], a1);
                }
            }
        }
        red[0][cq][p] = a0;
        red[1][cq][p] = a1;
    }
    __syncthreads();
    if (t < 128) {
        int ch = t >> 6;       // 0 = h, 1 = w
        int pp = t & 63;
        float flo = (float)lo_p[0];
        float fhi = (float)hi_p[0];
        float sv = red[ch][0][pp] + red[ch][1][pp] + red[ch][2][pp]
                 + red[ch][3][pp] + boff[ch];
        float gg = 1.f / (1.f + expf(-sv));
        rfs[ch][pp] = (flo + (fhi - flo) * gg) * 0.5f;   // pre-halved
    }
    __syncthreads();

    // ---------------- phase 1: barrier-free sample + MFMA ----------------
    int lane = t & 63;
    int wv   = t >> 6;
    int nidx = lane & 15;
    int quad = lane >> 4;
    int px   = wv * 16 + nidx;       // this thread's pixel in the segment

    float rh = rfs[0][px];
    float rw = rfs[1][px];
    float fy = (float)y;
    float fx = (float)(xb + px);
    const float* xc0 = xin + (size_t)b * CC * HWP + (size_t)(quad * 8) * HWP;

    f32x4 acc[4] = {};

    for (int k = 0; k < 9; ++k) {
        float dy = (float)(k / 3 - 1);
        float dx = (float)(k % 3 - 1);
        float ys = fy + dy * rh;
        float xs = fx + dx * rw;
        float y0f = floorf(ys), x0f = floorf(xs);
        float ty = ys - y0f, tx = xs - x0f;
        int iy0 = min(max((int)y0f, 0), HH - 1);
        int iy1 = min(iy0 + 1, HH - 1);
        int ix0 = min(max((int)x0f, 0), WWD - 1);
        int ix1 = min(ix0 + 1, WWD - 1);
        float w00 = (1.f - ty) * (1.f - tx);
        float w01 = (1.f - ty) * tx;
        float w10 = ty * (1.f - tx);
        float w11 = ty * tx;
        int o00 = iy0 * WWD + ix0, o01 = iy0 * WWD + ix1;
        int o10 = iy1 * WWD + ix0, o11 = iy1 * WWD + ix1;

        // sample 16 channels straight into hi/lo B-fragments
        union { unsigned short h[8]; bf16x8 v; } b0h, b0l, b1h, b1l;
        {
            const float* xc = xc0;
#pragma unroll
            for (int j = 0; j < 8; ++j) {
                float sv = w00 * xc[o00] + w01 * xc[o01]
                         + w10 * xc[o10] + w11 * xc[o11];
                unsigned short hs = bf16_rne(sv);
                b0h.h[j] = hs;
                b0l.h[j] = bf16_rne(sv - bf16_tof(hs));
                xc += HWP;
            }
            xc = xc0 + (size_t)32 * HWP;
#pragma unroll
            for (int j = 0; j < 8; ++j) {
                float sv = w00 * xc[o00] + w01 * xc[o01]
                         + w10 * xc[o10] + w11 * xc[o11];
                unsigned short hs = bf16_rne(sv);
                b1h.h[j] = hs;
                b1l.h[j] = bf16_rne(sv - bf16_tof(hs));
                xc += HWP;
            }
        }

        // A hi/lo fragments from global (L1/L2-hot: 32 KB working set per tap)
        const unsigned short* whk = Whi + (size_t)k * OO * CC + nidx * CC + quad * 8;
        const unsigned short* wlk = Wlo + (size_t)k * OO * CC + nidx * CC + quad * 8;
#pragma unroll
        for (int mt = 0; mt < 4; ++mt) {
            bf16x8 ah0 = *(const bf16x8*)(whk + mt * 16 * CC);        // ks=0
            bf16x8 al0 = *(const bf16x8*)(wlk + mt * 16 * CC);
            acc[mt] = __builtin_amdgcn_mfma_f32_16x16x32_bf16(ah0, b0h.v, acc[mt], 0, 0, 0);
            acc[mt] = __builtin_amdgcn_mfma_f32_16x16x32_bf16(al0, b0h.v, acc[mt], 0, 0, 0);
            acc[mt] = __builtin_amdgcn_mfma_f32_16x16x32_bf16(ah0, b0l.v, acc[mt], 0, 0, 0);
            bf16x8 ah1 = *(const bf16x8*)(whk + mt * 16 * CC + 32);   // ks=1
            bf16x8 al1 = *(const bf16x8*)(wlk + mt * 16 * CC + 32);
            acc[mt] = __builtin_amdgcn_mfma_f32_16x16x32_bf16(ah1, b1h.v, acc[mt], 0, 0, 0);
            acc[mt] = __builtin_amdgcn_mfma_f32_16x16x32_bf16(al1, b1h.v, acc[mt], 0, 0, 0);
            acc[mt] = __builtin_amdgcn_mfma_f32_16x16x32_bf16(ah1, b1l.v, acc[mt], 0, 0, 0);
        }
    }

    // ---------------- epilogue ----------------
    int pxg = p0 + px;
#pragma unroll
    for (int mt = 0; mt < 4; ++mt) {
#pragma unroll
        for (int rr = 0; rr < 4; ++rr) {
            int o = mt * 16 + quad * 4 + rr;
            float v = acc[mt][rr] + bias[o];
            size_t idx = (size_t)(b * OO + o) * HWP + pxg;
            if (mode == 1) v = fmaxf(v, 0.f);
            else           v += resid[idx];
            out[idx] = v;
        }
    }
}

// ---------------------------------------------------------------------------
extern "C" void kernel_launch(void* const* d_in, const int* in_sizes, int n_in,
                              void* d_out, int out_size, void* d_ws, size_t ws_size,
                              hipStream_t stream) {
    const float* x      = (const float*)d_in[0];
    const float* w_off1 = (const float*)d_in[1];
    const float* b_off1 = (const float*)d_in[2];
    const float* W1     = (const float*)d_in[3];
    const float* b1     = (const float*)d_in[4];
    const float* w_off2 = (const float*)d_in[5];
    const float* b_off2 = (const float*)d_in[6];
    const float* W2     = (const float*)d_in[7];
    const float* b2     = (const float*)d_in[8];
    const int*   lo_p   = (const int*)d_in[10];
    const int*   hi_p   = (const int*)d_in[11];
    float* outp = (float*)d_out;

    float* wsf = (float*)d_ws;
    float* t1  = wsf;                                        // B*C*HW f32
    unsigned short* Wh1 = (unsigned short*)(t1 + (size_t)BB * CC * HWP);
    unsigned short* Wl1 = Wh1 + OO * CC * 9;                 // 36864 each
    unsigned short* Wh2 = Wl1 + OO * CC * 9;
    unsigned short* Wl2 = Wh2 + OO * CC * 9;

    // 1. transpose + hi/lo split both weight tensors
    wtrans_kernel<<<288, 256, 0, stream>>>(W1, W2, Wh1, Wl1, Wh2, Wl2);

    // 2. layer 1: fused offsets + arconv + relu -> t1
    arconv_kernel<<<1024, 256, 0, stream>>>(x, Wh1, Wl1, w_off1, b_off1, b1,
                                            lo_p, hi_p, nullptr, t1, 1);

    // 3. layer 2: fused offsets + arconv + residual -> out
    arconv_kernel<<<1024, 256, 0, stream>>>(t1, Wh2, Wl2, w_off2, b_off2, b2,
                                            lo_p, hi_p, x, outp, 2);
}